// Round 20
// baseline (314.851 us; speedup 1.0000x reference)
//
#include <hip/hip_runtime.h>
#include <hip/hip_fp16.h>

// EllipticGNN: 2-layer GCN + linear head, f32 accumulate.
// R20 = R19 + two-pass 8-bucket CSR fill:
//   pass1: single edge-stream read -> 8 per-XCD packed buckets (block-level
//          slot reservation, LDS rank atomics).
//   pass2: XCD-pinned scatter from own bucket into padded col (L2-local).
// fp16 pre-scaled gather rows; pure-gather aggs; dot2 gemm1 + dense tail.

constexpr int NN   = 100000;
constexpr int NE   = 1600000;
constexpr int FIN  = 165;
constexpr int HID  = 128;
constexpr int CAP  = 64;                // padded row capacity (P(deg>64)~0)
constexpr int NPX  = NN / 8;            // 12500 nodes per XCD partition
constexpr int K2_1 = (FIN + 1) / 2;     // 83 k-pairs for layer 1
constexpr int NB_G = (NN + 63) / 64;    // 1563 gemm/tail tiles
constexpr int BKCAP = 210000;           // per-bucket capacity (24 sigma)
constexpr int EPB1 = 2048;              // edges per pass-1 block
constexpr int NB1  = (NE + EPB1 - 1) / EPB1;   // 782
constexpr int EPB2 = 2048;
constexpr int NB2C = (BKCAP + EPB2 - 1) / EPB2; // 103 chunks per bucket

typedef _Float16 h2v __attribute__((ext_vector_type(2)));

__device__ __forceinline__ float fdot2u(unsigned a, unsigned b, float c) {
#if __has_builtin(__builtin_amdgcn_fdot2)
    return __builtin_amdgcn_fdot2(__builtin_bit_cast(h2v, a),
                                  __builtin_bit_cast(h2v, b), c, false);
#else
    __half2 ah = __builtin_bit_cast(__half2, a);
    __half2 bh = __builtin_bit_cast(__half2, b);
    float2 af = __half22float2(ah), bf = __half22float2(bh);
    return fmaf(af.x, bf.x, fmaf(af.y, bf.y, c));
#endif
}

// Merged W1+W2 pack into k-pair half2 layout; also zeroes bcur[8].
__global__ __launch_bounds__(256) void k_wpack(const float* __restrict__ W1,
                                               const float* __restrict__ W2,
                                               unsigned* __restrict__ W1p,
                                               unsigned* __restrict__ W2p,
                                               int* __restrict__ bcur) {
    int idx = blockIdx.x * 256 + threadIdx.x;
    if (idx < 8) bcur[idx] = 0;
    if (idx < 64 * 128) {
        int k2 = idx >> 7, c = idx & 127;
        __half2 h = __floats2half2_rn(W2[(2 * k2) * HID + c],
                                      W2[(2 * k2 + 1) * HID + c]);
        W2p[idx] = __builtin_bit_cast(unsigned, h);
    } else {
        int j = idx - 64 * 128;
        if (j >= K2_1 * HID) return;
        int k2 = j / HID, c = j % HID;
        float lo = W1[(2 * k2) * HID + c];
        float hi = (2 * k2 + 1 < FIN) ? W1[(2 * k2 + 1) * HID + c] : 0.0f;
        __half2 h = __floats2half2_rn(lo, hi);
        W1p[j] = __builtin_bit_cast(unsigned, h);
    }
}

// Pass 1: edge chunk -> 8 packed buckets. One stream read; block reserves
// slots in bulk (one global atomic per bucket). Also zeroes cur slice.
__global__ __launch_bounds__(256) void k_bucket8(const int* __restrict__ src,
                                                 const int* __restrict__ dst,
                                                 int* __restrict__ bcur,
                                                 unsigned* __restrict__ tmp,
                                                 int* __restrict__ cur) {
    __shared__ int lcnt[8];
    __shared__ int lbase[8];
    const int b = blockIdx.x;
    const int t = threadIdx.x;
    {   // zero cur slice (782 blocks x 128 >= NN)
        int z = b * 128 + (t & 127);
        if (t < 128 && z < NN) cur[z] = 0;
    }
    if (t < 8) lcnt[t] = 0;
    __syncthreads();
    const int e0 = b * EPB1;
    const int e1 = (e0 + EPB1 < NE) ? e0 + EPB1 : NE;

    int myb[8], myp[8], myr[8];
    bool ok[8];
#pragma unroll
    for (int u = 0; u < 8; ++u) {
        int e = e0 + t + u * 256;
        ok[u] = (e < e1);
        myb[u] = 0; myp[u] = 0; myr[u] = 0;
        if (ok[u]) {
            int d = __builtin_nontemporal_load(&dst[e]);
            int s = __builtin_nontemporal_load(&src[e]);
            int bk = (int)((unsigned)d / (unsigned)NPX);
            int dl = d - bk * NPX;
            myb[u] = bk;
            myp[u] = s | (dl << 17);
            myr[u] = atomicAdd(&lcnt[bk], 1);
        }
    }
    __syncthreads();
    if (t < 8) lbase[t] = atomicAdd(&bcur[t], lcnt[t]);
    __syncthreads();
#pragma unroll
    for (int u = 0; u < 8; ++u) {
        if (ok[u]) {
            int bk = myb[u];
            tmp[(size_t)bk * BKCAP + lbase[bk] + myr[u]] = (unsigned)myp[u];
        }
    }
}

// Pass 2: XCD b scatters its own bucket into its col partition (L2-local).
// cur[d] ends as degree of d.
__global__ __launch_bounds__(256) void k_scatter8(const unsigned* __restrict__ tmp,
                                                  const int* __restrict__ bcur,
                                                  int* __restrict__ cur,
                                                  int* __restrict__ col) {
    const int bk = blockIdx.x & 7;
    const int ch = blockIdx.x >> 3;
    const int cnt = bcur[bk];
    const int i0 = ch * EPB2;
    if (i0 >= cnt) return;
    const int i1 = (i0 + EPB2 < cnt) ? i0 + EPB2 : cnt;
    const unsigned* tb = tmp + (size_t)bk * BKCAP;
    const int dbase = bk * NPX;
    int i = i0 + threadIdx.x;
    for (; i + 3 * 256 < i1; i += 4 * 256) {
        unsigned p0 = tb[i];
        unsigned p1 = tb[i + 256];
        unsigned p2 = tb[i + 512];
        unsigned p3 = tb[i + 768];
        int d0 = dbase + (int)(p0 >> 17);
        int d1 = dbase + (int)(p1 >> 17);
        int d2 = dbase + (int)(p2 >> 17);
        int d3 = dbase + (int)(p3 >> 17);
        col[d0 * CAP + atomicAdd(&cur[d0], 1)] = (int)(p0 & 0x1FFFFu);
        col[d1 * CAP + atomicAdd(&cur[d1], 1)] = (int)(p1 & 0x1FFFFu);
        col[d2 * CAP + atomicAdd(&cur[d2], 1)] = (int)(p2 & 0x1FFFFu);
        col[d3 * CAP + atomicAdd(&cur[d3], 1)] = (int)(p3 & 0x1FFFFu);
    }
    for (; i < i1; i += 256) {
        unsigned pk = tb[i];
        int d = dbase + (int)(pk >> 17);
        col[d * CAP + atomicAdd(&cur[d], 1)] = (int)(pk & 0x1FFFFu);
    }
}

// Layer-1 GEMM via dot2: 64-row tile, 8 rows x 4 cols per thread.
// dinv computed inline from cnt.
__global__ __launch_bounds__(256) void k_gemm1(const float* __restrict__ X,
                                               const unsigned* __restrict__ W1p,
                                               const int* __restrict__ cnt,
                                               __half* __restrict__ Yh) {
    constexpr int K = FIN;           // 165
    constexpr int KPH = 168;         // half stride per row (84 uints)
    constexpr int KPU = 84;
    __shared__ __half Xs[64 * KPH];
    const int tid = threadIdx.x;
    const long base = (long)blockIdx.x * 64;
    const int rows = (NN - base < 64) ? (int)(NN - base) : 64;

    const float* Xg = X + base * K;
    for (int i = tid; i < rows * K; i += 256) {
        int r = i / K, c = i % K;
        Xs[r * KPH + c] = __float2half(Xg[i]);
    }
    for (int i = tid; i < 64 * 3; i += 256) {        // zero pad c=165..167
        int r = i / 3, c = K + i % 3;
        Xs[r * KPH + c] = __float2half(0.f);
    }
    if (rows < 64) {
        for (int i = tid; i < (64 - rows) * KPH; i += 256)
            Xs[rows * KPH + i] = __float2half(0.f);
    }
    __syncthreads();

    const int cg = tid & 31;
    const int rg = tid >> 5;
    const unsigned* Wp = W1p + 4 * cg;
    const unsigned* XrowU = (const unsigned*)&Xs[rg * 8 * KPH];

    float acc[8][4];
#pragma unroll
    for (int r = 0; r < 8; ++r)
#pragma unroll
        for (int c = 0; c < 4; ++c) acc[r][c] = 0.0f;

    int k2 = 0;
    for (; k2 + 2 <= K2_1; k2 += 2) {               // 41 iters (82 pairs)
        uint4 w0 = *(const uint4*)(Wp + (k2 + 0) * HID);
        uint4 w1 = *(const uint4*)(Wp + (k2 + 1) * HID);
#pragma unroll
        for (int r = 0; r < 8; ++r) {
            uint2 xp = *(const uint2*)&XrowU[r * KPU + k2];   // 8B LDS
            acc[r][0] = fdot2u(xp.x, w0.x, acc[r][0]);
            acc[r][1] = fdot2u(xp.x, w0.y, acc[r][1]);
            acc[r][2] = fdot2u(xp.x, w0.z, acc[r][2]);
            acc[r][3] = fdot2u(xp.x, w0.w, acc[r][3]);
            acc[r][0] = fdot2u(xp.y, w1.x, acc[r][0]);
            acc[r][1] = fdot2u(xp.y, w1.y, acc[r][1]);
            acc[r][2] = fdot2u(xp.y, w1.z, acc[r][2]);
            acc[r][3] = fdot2u(xp.y, w1.w, acc[r][3]);
        }
    }
    {   // leftover pair k2 = 82 (covers k=164 + zero pad)
        uint4 wt = *(const uint4*)(Wp + k2 * HID);
#pragma unroll
        for (int r = 0; r < 8; ++r) {
            unsigned xp = XrowU[r * KPU + k2];
            acc[r][0] = fdot2u(xp, wt.x, acc[r][0]);
            acc[r][1] = fdot2u(xp, wt.y, acc[r][1]);
            acc[r][2] = fdot2u(xp, wt.z, acc[r][2]);
            acc[r][3] = fdot2u(xp, wt.w, acc[r][3]);
        }
    }

#pragma unroll
    for (int r = 0; r < 8; ++r) {
        long row = base + rg * 8 + r;
        if (row < NN) {
            float d = rsqrtf((float)cnt[row] + 1.0f);
            __half2 p0 = __floats2half2_rn(acc[r][0] * d, acc[r][1] * d);
            __half2 p1 = __floats2half2_rn(acc[r][2] * d, acc[r][3] * d);
            uint2 uv;
            uv.x = *reinterpret_cast<unsigned int*>(&p0);
            uv.y = *reinterpret_cast<unsigned int*>(&p1);
            *reinterpret_cast<uint2*>(&Yh[row * HID + 4 * cg]) = uv;
        }
    }
}

// Gather sum of pre-scaled fp16 rows (incl. self) from padded col rows;
// lane j owns cols 2j,2j+1.
__device__ __forceinline__ void gather_row_h(const __half2* __restrict__ H2,
                                             const int* __restrict__ col,
                                             int i, int cnt, int j,
                                             float& a0, float& a1) {
    const int base = i * CAP;
    float2 self = __half22float2(H2[(size_t)i * 64 + j]);
    a0 = self.x;
    a1 = self.y;
    int k = 0;
    for (; k + 8 <= cnt; k += 8) {
        int s[8];
#pragma unroll
        for (int u = 0; u < 8; ++u)
            s[u] = __builtin_nontemporal_load(&col[base + k + u]);
        __half2 h[8];
#pragma unroll
        for (int u = 0; u < 8; ++u) h[u] = H2[(size_t)s[u] * 64 + j];
#pragma unroll
        for (int u = 0; u < 8; ++u) {
            float2 f = __half22float2(h[u]);
            a0 += f.x;
            a1 += f.y;
        }
    }
    for (; k < cnt; ++k) {
        int cs = __builtin_nontemporal_load(&col[base + k]);
        float2 f = __half22float2(H2[(size_t)cs * 64 + j]);
        a0 += f.x;
        a1 += f.y;
    }
}

// Pure gather, wave per 4 nodes. dinv inline from cnt.
// MODE 0: out = fp16( di * relu(di*a + b1) );  MODE 1: out = fp16( di * a ).
template<int MODE>
__global__ __launch_bounds__(64) void k_aggP(const __half* __restrict__ Hh,
                                             const int* __restrict__ cntA,
                                             const int* __restrict__ col,
                                             const float* __restrict__ bias,
                                             __half* __restrict__ Oh) {
    const int j = threadIdx.x;
    const int base = blockIdx.x * 4;
    const __half2* H2 = (const __half2*)Hh;
    float2 bb = make_float2(0.f, 0.f);
    if (MODE == 0) bb = ((const float2*)bias)[j];

#pragma unroll
    for (int n = 0; n < 4; ++n) {
        const int i = base + n;
        const int cnt = cntA[i];
        const float di = rsqrtf((float)cnt + 1.0f);
        float a0, a1;
        gather_row_h(H2, col, i, cnt, j, a0, a1);
        float r0, r1;
        if (MODE == 0) {
            r0 = di * fmaxf(di * a0 + bb.x, 0.0f);
            r1 = di * fmaxf(di * a1 + bb.y, 0.0f);
        } else {
            r0 = di * a0;
            r1 = di * a1;
        }
        ((__half2*)Oh)[(size_t)i * 64 + j] = __floats2half2_rn(r0, r1);
    }
}

// Dense tail: out[i] = relu(u[i] @ W2 + b2) @ W3 + b3, u fp16, dot2 math.
__global__ __launch_bounds__(256) void k_tail(const unsigned* __restrict__ Ug,
                                              const unsigned* __restrict__ W2p,
                                              const float* __restrict__ b2,
                                              const float* __restrict__ W3,
                                              const float* __restrict__ b3,
                                              float* __restrict__ out) {
    __shared__ unsigned Xs[64 * 66];         // [row][k2], stride 66
    __shared__ unsigned Ws[64 * 128];        // [k2][c]
    const int tid = threadIdx.x;
    const long base = (long)blockIdx.x * 64;

#pragma unroll
    for (int i = 0; i < 4; ++i) {
        int li = tid + i * 256;               // uint4 index, 1024 total
        int row = li >> 4;
        int q4  = li & 15;
        uint4 v = make_uint4(0, 0, 0, 0);
        if (base + row < NN)
            v = *(const uint4*)&Ug[(base + row) * 64 + q4 * 4];
        Xs[row * 66 + q4 * 4 + 0] = v.x;
        Xs[row * 66 + q4 * 4 + 1] = v.y;
        Xs[row * 66 + q4 * 4 + 2] = v.z;
        Xs[row * 66 + q4 * 4 + 3] = v.w;
    }
#pragma unroll
    for (int i = 0; i < 8; ++i) {
        int li = tid + i * 256;               // uint4 index, 2048 total
        *(uint4*)&Ws[li * 4] = *(const uint4*)&W2p[li * 4];
    }
    __syncthreads();

    const int cg = tid & 31;
    const int rg = tid >> 5;

    float acc[8][4];
#pragma unroll
    for (int r = 0; r < 8; ++r)
#pragma unroll
        for (int c = 0; c < 4; ++c) acc[r][c] = 0.0f;

    for (int k2 = 0; k2 < 64; k2 += 2) {
        uint4 w0 = *(const uint4*)&Ws[k2 * 128 + 4 * cg];
        uint4 w1 = *(const uint4*)&Ws[(k2 + 1) * 128 + 4 * cg];
#pragma unroll
        for (int r = 0; r < 8; ++r) {
            uint2 xp = *(const uint2*)&Xs[(rg * 8 + r) * 66 + k2];
            acc[r][0] = fdot2u(xp.x, w0.x, acc[r][0]);
            acc[r][1] = fdot2u(xp.x, w0.y, acc[r][1]);
            acc[r][2] = fdot2u(xp.x, w0.z, acc[r][2]);
            acc[r][3] = fdot2u(xp.x, w0.w, acc[r][3]);
            acc[r][0] = fdot2u(xp.y, w1.x, acc[r][0]);
            acc[r][1] = fdot2u(xp.y, w1.y, acc[r][1]);
            acc[r][2] = fdot2u(xp.y, w1.z, acc[r][2]);
            acc[r][3] = fdot2u(xp.y, w1.w, acc[r][3]);
        }
    }

    const float4 bb = *(const float4*)&b2[4 * cg];
    float2 w3v[4];
#pragma unroll
    for (int c = 0; c < 4; ++c)
        w3v[c] = *(const float2*)&W3[(4 * cg + c) * 2];
    const float b30 = b3[0], b31 = b3[1];

#pragma unroll
    for (int r = 0; r < 8; ++r) {
        float h0 = fmaxf(acc[r][0] + bb.x, 0.f);
        float h1 = fmaxf(acc[r][1] + bb.y, 0.f);
        float h2 = fmaxf(acc[r][2] + bb.z, 0.f);
        float h3 = fmaxf(acc[r][3] + bb.w, 0.f);
        float p0 = h0 * w3v[0].x + h1 * w3v[1].x + h2 * w3v[2].x + h3 * w3v[3].x;
        float p1 = h0 * w3v[0].y + h1 * w3v[1].y + h2 * w3v[2].y + h3 * w3v[3].y;
#pragma unroll
        for (int m = 1; m < 32; m <<= 1) {
            p0 += __shfl_xor(p0, m);
            p1 += __shfl_xor(p1, m);
        }
        long row = base + rg * 8 + r;
        if (cg == 0 && row < NN)
            ((float2*)out)[row] = make_float2(p0 + b30, p1 + b31);
    }
}

extern "C" void kernel_launch(void* const* d_in, const int* in_sizes, int n_in,
                              void* d_out, int out_size, void* d_ws, size_t ws_size,
                              hipStream_t stream) {
    const float* x   = (const float*)d_in[0];
    const int*   ei  = (const int*)d_in[1];
    const float* W1  = (const float*)d_in[2];
    const float* b1  = (const float*)d_in[3];
    const float* W2  = (const float*)d_in[4];
    const float* b2  = (const float*)d_in[5];
    const float* W3  = (const float*)d_in[6];
    const float* b3  = (const float*)d_in[7];
    float* out = (float*)d_out;

    const int* srcA = ei;
    const int* dstA = ei + NE;

    char* p = (char*)d_ws;
    auto alloc = [&](size_t bytes) {
        char* r = p;
        p += (bytes + 255) & ~(size_t)255;
        return r;
    };
    int*      cur    = (int*)  alloc(NN * 4);        // cursor == degree
    int*      bcur   = (int*)  alloc(8 * 4);
    unsigned* tmp    = (unsigned*)alloc((size_t)8 * BKCAP * 4);   // 6.72MB
    int*      col    = (int*)  alloc((size_t)NN * CAP * 4);       // 25.6MB
    unsigned* w2pk   = (unsigned*)alloc(64 * 128 * 4);
    unsigned* w1pk   = (unsigned*)alloc(K2_1 * HID * 4);
    __half*   hhat   = (__half*)alloc((size_t)NN * HID * 2);  // dinv*h1
    __half*   h2hat  = (__half*)alloc((size_t)NN * HID * 2);  // dinv*h2
    __half*   ubuf   = (__half*)alloc((size_t)NN * HID * 2);  // A-hat h2

    const int nb_wp = (64 * 128 + K2_1 * HID + 255) / 256;

    // ---- weight packs (+ bcur zero) ----
    k_wpack<<<nb_wp, 256, 0, stream>>>(W1, W2, w1pk, w2pk, bcur);

    // ---- pass 1: bucket edges (also zeroes cur) ----
    k_bucket8<<<NB1, 256, 0, stream>>>(srcA, dstA, bcur, tmp, cur);

    // ---- pass 2: XCD-local scatter into padded col ----
    k_scatter8<<<8 * NB2C, 256, 0, stream>>>(tmp, bcur, cur, col);

    // ---- layer 1 GEMM (dot2) -> hhat ----
    k_gemm1<<<NB_G, 256, 0, stream>>>(x, w1pk, cur, hhat);

    // ---- agg1 (pure) -> h2hat ----
    k_aggP<0><<<NN / 4, 64, 0, stream>>>(hhat, cur, col, b1, h2hat);

    // ---- agg2 (pure) -> u ----
    k_aggP<1><<<NN / 4, 64, 0, stream>>>(h2hat, cur, col, nullptr, ubuf);

    // ---- tail: relu(u@W2+b2)@W3+b3 ----
    k_tail<<<NB_G, 256, 0, stream>>>((const unsigned*)ubuf, w2pk, b2, W3, b3, out);
}

// Round 21
// 283.935 us; speedup vs baseline: 1.1089x; 1.1089x over previous
//
#include <hip/hip_runtime.h>
#include <hip/hip_fp16.h>

// EllipticGNN: 2-layer GCN + linear head, f32 accumulate.
// R21 = R19 (best passing, 309.5us) with gemm1 moved to MFMA
// (v_mfma_f32_16x16x32_f16, fp16 inputs, f32 accum). Tail stays dot2.
// Padded fixed-capacity CSR (fill cursor == degree histogram).

constexpr int NN   = 100000;
constexpr int NE   = 1600000;
constexpr int FIN  = 165;
constexpr int HID  = 128;
constexpr int CAP  = 64;                // padded row capacity (P(deg>64)~0)
constexpr int NPX  = NN / 8;            // 12500 nodes per XCD partition
constexpr int NCHUNK = 250;             // edge chunks per XCD
constexpr int EPC  = (NE + NCHUNK - 1) / NCHUNK;   // 6400 edges per chunk
constexpr int NB_G = (NN + 63) / 64;    // 1563 gemm/tail tiles
constexpr int KBLK = 24;                // 192/8 k-blocks for MFMA W1 pack

typedef _Float16 h2v  __attribute__((ext_vector_type(2)));
typedef _Float16 f16x8 __attribute__((ext_vector_type(8)));
typedef float    f32x4 __attribute__((ext_vector_type(4)));

__device__ __forceinline__ float fdot2u(unsigned a, unsigned b, float c) {
#if __has_builtin(__builtin_amdgcn_fdot2)
    return __builtin_amdgcn_fdot2(__builtin_bit_cast(h2v, a),
                                  __builtin_bit_cast(h2v, b), c, false);
#else
    __half2 ah = __builtin_bit_cast(__half2, a);
    __half2 bh = __builtin_bit_cast(__half2, b);
    float2 af = __half22float2(ah), bf = __half22float2(bh);
    return fmaf(af.x, bf.x, fmaf(af.y, bf.y, c));
#endif
}

__global__ __launch_bounds__(256) void k_zero_cur(int* __restrict__ cur) {
    int i = blockIdx.x * 256 + threadIdx.x;
    if (i < NN) cur[i] = 0;
}

// Weight packs: W2 -> k-pair half2 (dot2 tail); W1 -> MFMA B-layout
// Wb[kblk][c] = 8 consecutive-k halves of column c (zero-padded past K=165).
__global__ __launch_bounds__(256) void k_wpack(const float* __restrict__ W1,
                                               const float* __restrict__ W2,
                                               uint4* __restrict__ Wb,
                                               unsigned* __restrict__ W2p) {
    int idx = blockIdx.x * 256 + threadIdx.x;
    if (idx < 64 * 128) {
        int k2 = idx >> 7, c = idx & 127;
        __half2 h = __floats2half2_rn(W2[(2 * k2) * HID + c],
                                      W2[(2 * k2 + 1) * HID + c]);
        W2p[idx] = __builtin_bit_cast(unsigned, h);
    } else {
        int j = idx - 64 * 128;
        if (j >= KBLK * HID) return;
        int kb = j >> 7, c = j & 127;
        unsigned u[4];
#pragma unroll
        for (int q = 0; q < 4; ++q) {
            int k0 = kb * 8 + 2 * q;
            float lo = (k0     < FIN) ? W1[(size_t)k0 * HID + c] : 0.0f;
            float hi = (k0 + 1 < FIN) ? W1[(size_t)(k0 + 1) * HID + c] : 0.0f;
            __half2 h = __floats2half2_rn(lo, hi);
            u[q] = __builtin_bit_cast(unsigned, h);
        }
        Wb[j] = make_uint4(u[0], u[1], u[2], u[3]);
    }
}

// XCD-partitioned padded fill: col[d*CAP + slot] = s; cur[d] ends as degree.
__global__ __launch_bounds__(256) void k_fill_pad(const int* __restrict__ src,
                                                  const int* __restrict__ dst,
                                                  int* __restrict__ cur,
                                                  int* __restrict__ col) {
    const int b  = blockIdx.x;
    const int lo = (b & 7) * NPX;
    const int hi = lo + NPX;
    const int q  = b >> 3;
    const int e0 = q * EPC;
    const int e1 = (e0 + EPC < NE) ? e0 + EPC : NE;

    int e = e0 + threadIdx.x;
    for (; e + 3 * 256 < e1; e += 4 * 256) {
        int d0 = __builtin_nontemporal_load(&dst[e]);
        int d1 = __builtin_nontemporal_load(&dst[e + 256]);
        int d2 = __builtin_nontemporal_load(&dst[e + 512]);
        int d3 = __builtin_nontemporal_load(&dst[e + 768]);
        int s0 = __builtin_nontemporal_load(&src[e]);
        int s1 = __builtin_nontemporal_load(&src[e + 256]);
        int s2 = __builtin_nontemporal_load(&src[e + 512]);
        int s3 = __builtin_nontemporal_load(&src[e + 768]);
        if (d0 >= lo && d0 < hi) col[d0 * CAP + atomicAdd(&cur[d0], 1)] = s0;
        if (d1 >= lo && d1 < hi) col[d1 * CAP + atomicAdd(&cur[d1], 1)] = s1;
        if (d2 >= lo && d2 < hi) col[d2 * CAP + atomicAdd(&cur[d2], 1)] = s2;
        if (d3 >= lo && d3 < hi) col[d3 * CAP + atomicAdd(&cur[d3], 1)] = s3;
    }
    for (; e < e1; e += 256) {
        int d = __builtin_nontemporal_load(&dst[e]);
        if (d >= lo && d < hi) {
            int s = __builtin_nontemporal_load(&src[e]);
            col[d * CAP + atomicAdd(&cur[d], 1)] = s;
        }
    }
}

// Layer-1 GEMM via MFMA 16x16x32 f16. Block: 64 rows x 128 cols, 4 waves;
// wave w owns rows 16w..16w+15 as 8 16x16 tiles. K padded to 192 (6 steps).
// A from LDS fp16 (stride 200 halves: 2-way conflict only); B from Wb pack.
// Epilogue: fp16(dinv * y) with dinv = rsqrt(cnt+1).
__global__ __launch_bounds__(256) void k_gemm1m(const float* __restrict__ X,
                                                const uint4* __restrict__ Wb,
                                                const int* __restrict__ cnt,
                                                __half* __restrict__ Yh) {
    constexpr int KPH = 200;               // halves per LDS row (400B)
    __shared__ __half Xs[64 * KPH];        // 25.6 KB
    const int tid = threadIdx.x;
    const long base = (long)blockIdx.x * 64;
    const int rows = (NN - base < 64) ? (int)(NN - base) : 64;

    // stage X -> fp16 LDS
    for (int i = tid; i < rows * FIN; i += 256) {
        int r = i / FIN, c = i % FIN;
        Xs[r * KPH + c] = __float2half(X[base * FIN + i]);
    }
    for (int i = tid; i < 64 * 27; i += 256) {       // zero pad k=165..191
        int r = i / 27, c = FIN + i % 27;
        Xs[r * KPH + c] = __float2half(0.0f);
    }
    if (rows < 64) {
        for (int i = tid; i < (64 - rows) * KPH; i += 256)
            Xs[rows * KPH + i] = __float2half(0.0f);
    }
    __syncthreads();

    const int w   = tid >> 6;              // wave 0..3
    const int l   = tid & 63;
    const int l16 = l & 15;
    const int lq  = l >> 4;

    f32x4 acc[8];
#pragma unroll
    for (int n = 0; n < 8; ++n) acc[n] = (f32x4){0.f, 0.f, 0.f, 0.f};

    const __half* Arow = &Xs[(16 * w + l16) * KPH + lq * 8];
#pragma unroll
    for (int s = 0; s < 6; ++s) {
        f16x8 a = *(const f16x8*)(Arow + s * 32);            // ds_read_b128
        const uint4* bp = &Wb[(4 * s + lq) * HID + l16];
#pragma unroll
        for (int n = 0; n < 8; ++n) {
            f16x8 b = __builtin_bit_cast(f16x8, bp[16 * n]);
            acc[n] = __builtin_amdgcn_mfma_f32_16x16x32_f16(a, b, acc[n], 0, 0, 0);
        }
    }

    // epilogue: C/D mapping col = l&15, row = lq*4 + reg (within 16x16 tile)
    long rowR[4];
    float dR[4];
#pragma unroll
    for (int reg = 0; reg < 4; ++reg) {
        rowR[reg] = base + 16 * w + lq * 4 + reg;
        dR[reg] = (rowR[reg] < NN) ? rsqrtf((float)cnt[rowR[reg]] + 1.0f) : 0.f;
    }
#pragma unroll
    for (int n = 0; n < 8; ++n) {
        int colc = 16 * n + l16;
#pragma unroll
        for (int reg = 0; reg < 4; ++reg) {
            if (rowR[reg] < NN)
                Yh[rowR[reg] * HID + colc] = __float2half(acc[n][reg] * dR[reg]);
        }
    }
}

// Gather sum of pre-scaled fp16 rows (incl. self) from padded col rows;
// lane j owns cols 2j,2j+1.
__device__ __forceinline__ void gather_row_h(const __half2* __restrict__ H2,
                                             const int* __restrict__ col,
                                             int i, int cnt, int j,
                                             float& a0, float& a1) {
    const int base = i * CAP;
    float2 self = __half22float2(H2[(size_t)i * 64 + j]);
    a0 = self.x;
    a1 = self.y;
    int k = 0;
    for (; k + 8 <= cnt; k += 8) {
        int s[8];
#pragma unroll
        for (int u = 0; u < 8; ++u)
            s[u] = __builtin_nontemporal_load(&col[base + k + u]);
        __half2 h[8];
#pragma unroll
        for (int u = 0; u < 8; ++u) h[u] = H2[(size_t)s[u] * 64 + j];
#pragma unroll
        for (int u = 0; u < 8; ++u) {
            float2 f = __half22float2(h[u]);
            a0 += f.x;
            a1 += f.y;
        }
    }
    for (; k < cnt; ++k) {
        int cs = __builtin_nontemporal_load(&col[base + k]);
        float2 f = __half22float2(H2[(size_t)cs * 64 + j]);
        a0 += f.x;
        a1 += f.y;
    }
}

// Pure gather, wave per 4 nodes. dinv inline from cnt.
// MODE 0: out = fp16( di * relu(di*a + b1) );  MODE 1: out = fp16( di * a ).
template<int MODE>
__global__ __launch_bounds__(64) void k_aggP(const __half* __restrict__ Hh,
                                             const int* __restrict__ cntA,
                                             const int* __restrict__ col,
                                             const float* __restrict__ bias,
                                             __half* __restrict__ Oh) {
    const int j = threadIdx.x;
    const int base = blockIdx.x * 4;
    const __half2* H2 = (const __half2*)Hh;
    float2 bb = make_float2(0.f, 0.f);
    if (MODE == 0) bb = ((const float2*)bias)[j];

#pragma unroll
    for (int n = 0; n < 4; ++n) {
        const int i = base + n;
        const int cnt = cntA[i];
        const float di = rsqrtf((float)cnt + 1.0f);
        float a0, a1;
        gather_row_h(H2, col, i, cnt, j, a0, a1);
        float r0, r1;
        if (MODE == 0) {
            r0 = di * fmaxf(di * a0 + bb.x, 0.0f);
            r1 = di * fmaxf(di * a1 + bb.y, 0.0f);
        } else {
            r0 = di * a0;
            r1 = di * a1;
        }
        ((__half2*)Oh)[(size_t)i * 64 + j] = __floats2half2_rn(r0, r1);
    }
}

// Dense tail: out[i] = relu(u[i] @ W2 + b2) @ W3 + b3, u fp16, dot2 math.
__global__ __launch_bounds__(256) void k_tail(const unsigned* __restrict__ Ug,
                                              const unsigned* __restrict__ W2p,
                                              const float* __restrict__ b2,
                                              const float* __restrict__ W3,
                                              const float* __restrict__ b3,
                                              float* __restrict__ out) {
    __shared__ unsigned Xs[64 * 66];         // [row][k2], stride 66
    __shared__ unsigned Ws[64 * 128];        // [k2][c]
    const int tid = threadIdx.x;
    const long base = (long)blockIdx.x * 64;

#pragma unroll
    for (int i = 0; i < 4; ++i) {
        int li = tid + i * 256;               // uint4 index, 1024 total
        int row = li >> 4;
        int q4  = li & 15;
        uint4 v = make_uint4(0, 0, 0, 0);
        if (base + row < NN)
            v = *(const uint4*)&Ug[(base + row) * 64 + q4 * 4];
        Xs[row * 66 + q4 * 4 + 0] = v.x;
        Xs[row * 66 + q4 * 4 + 1] = v.y;
        Xs[row * 66 + q4 * 4 + 2] = v.z;
        Xs[row * 66 + q4 * 4 + 3] = v.w;
    }
#pragma unroll
    for (int i = 0; i < 8; ++i) {
        int li = tid + i * 256;               // uint4 index, 2048 total
        *(uint4*)&Ws[li * 4] = *(const uint4*)&W2p[li * 4];
    }
    __syncthreads();

    const int cg = tid & 31;
    const int rg = tid >> 5;

    float acc[8][4];
#pragma unroll
    for (int r = 0; r < 8; ++r)
#pragma unroll
        for (int c = 0; c < 4; ++c) acc[r][c] = 0.0f;

    for (int k2 = 0; k2 < 64; k2 += 2) {
        uint4 w0 = *(const uint4*)&Ws[k2 * 128 + 4 * cg];
        uint4 w1 = *(const uint4*)&Ws[(k2 + 1) * 128 + 4 * cg];
#pragma unroll
        for (int r = 0; r < 8; ++r) {
            uint2 xp = *(const uint2*)&Xs[(rg * 8 + r) * 66 + k2];
            acc[r][0] = fdot2u(xp.x, w0.x, acc[r][0]);
            acc[r][1] = fdot2u(xp.x, w0.y, acc[r][1]);
            acc[r][2] = fdot2u(xp.x, w0.z, acc[r][2]);
            acc[r][3] = fdot2u(xp.x, w0.w, acc[r][3]);
            acc[r][0] = fdot2u(xp.y, w1.x, acc[r][0]);
            acc[r][1] = fdot2u(xp.y, w1.y, acc[r][1]);
            acc[r][2] = fdot2u(xp.y, w1.z, acc[r][2]);
            acc[r][3] = fdot2u(xp.y, w1.w, acc[r][3]);
        }
    }

    const float4 bb = *(const float4*)&b2[4 * cg];
    float2 w3v[4];
#pragma unroll
    for (int c = 0; c < 4; ++c)
        w3v[c] = *(const float2*)&W3[(4 * cg + c) * 2];
    const float b30 = b3[0], b31 = b3[1];

#pragma unroll
    for (int r = 0; r < 8; ++r) {
        float h0 = fmaxf(acc[r][0] + bb.x, 0.f);
        float h1 = fmaxf(acc[r][1] + bb.y, 0.f);
        float h2 = fmaxf(acc[r][2] + bb.z, 0.f);
        float h3 = fmaxf(acc[r][3] + bb.w, 0.f);
        float p0 = h0 * w3v[0].x + h1 * w3v[1].x + h2 * w3v[2].x + h3 * w3v[3].x;
        float p1 = h0 * w3v[0].y + h1 * w3v[1].y + h2 * w3v[2].y + h3 * w3v[3].y;
#pragma unroll
        for (int m = 1; m < 32; m <<= 1) {
            p0 += __shfl_xor(p0, m);
            p1 += __shfl_xor(p1, m);
        }
        long row = base + rg * 8 + r;
        if (cg == 0 && row < NN)
            ((float2*)out)[row] = make_float2(p0 + b30, p1 + b31);
    }
}

extern "C" void kernel_launch(void* const* d_in, const int* in_sizes, int n_in,
                              void* d_out, int out_size, void* d_ws, size_t ws_size,
                              hipStream_t stream) {
    const float* x   = (const float*)d_in[0];
    const int*   ei  = (const int*)d_in[1];
    const float* W1  = (const float*)d_in[2];
    const float* b1  = (const float*)d_in[3];
    const float* W2  = (const float*)d_in[4];
    const float* b2  = (const float*)d_in[5];
    const float* W3  = (const float*)d_in[6];
    const float* b3  = (const float*)d_in[7];
    float* out = (float*)d_out;

    const int* srcA = ei;
    const int* dstA = ei + NE;

    char* p = (char*)d_ws;
    auto alloc = [&](size_t bytes) {
        char* r = p;
        p += (bytes + 255) & ~(size_t)255;
        return r;
    };
    int*      cur    = (int*)  alloc(NN * 4);        // cursor == degree
    int*      col    = (int*)  alloc((size_t)NN * CAP * 4);   // padded 25.6MB
    unsigned* w2pk   = (unsigned*)alloc(64 * 128 * 4);
    uint4*    wb4    = (uint4*)alloc((size_t)KBLK * HID * 16); // 49KB
    __half*   hhat   = (__half*)alloc((size_t)NN * HID * 2);  // dinv*h1
    __half*   h2hat  = (__half*)alloc((size_t)NN * HID * 2);  // dinv*h2
    __half*   ubuf   = (__half*)alloc((size_t)NN * HID * 2);  // A-hat h2

    const int nb_n  = (NN + 255) / 256;
    const int nb_wp = (64 * 128 + KBLK * HID + 255) / 256;

    // ---- padded CSR fill (cursor == histogram) + weight packs ----
    k_zero_cur<<<nb_n, 256, 0, stream>>>(cur);
    k_wpack<<<nb_wp, 256, 0, stream>>>(W1, W2, wb4, w2pk);
    k_fill_pad<<<8 * NCHUNK, 256, 0, stream>>>(srcA, dstA, cur, col);

    // ---- layer 1 GEMM (MFMA) -> hhat ----
    k_gemm1m<<<NB_G, 256, 0, stream>>>(x, wb4, cur, hhat);

    // ---- agg1 (pure) -> h2hat ----
    k_aggP<0><<<NN / 4, 64, 0, stream>>>(hhat, cur, col, b1, h2hat);

    // ---- agg2 (pure) -> u ----
    k_aggP<1><<<NN / 4, 64, 0, stream>>>(h2hat, cur, col, nullptr, ubuf);

    // ---- tail: relu(u@W2+b2)@W3+b3 ----
    k_tail<<<NB_G, 256, 0, stream>>>((const unsigned*)ubuf, w2pk, b2, W3, b3, out);
}

// Round 22
// 261.191 us; speedup vs baseline: 1.2054x; 1.0871x over previous
//
#include <hip/hip_runtime.h>
#include <hip/hip_fp16.h>

// EllipticGNN: 2-layer GCN + linear head, f32 accumulate.
// R22 = R21 + tail moved to MFMA (same verified 16x16x32 f16 pattern as
// gemm1m): q = u@W2 via MFMA, relu+b2, xW3+b3 head via 16-lane reduce.
// Padded fixed-capacity CSR; fp16 pre-scaled gather rows; pure-gather aggs.

constexpr int NN   = 100000;
constexpr int NE   = 1600000;
constexpr int FIN  = 165;
constexpr int HID  = 128;
constexpr int CAP  = 64;                // padded row capacity (P(deg>64)~0)
constexpr int NPX  = NN / 8;            // 12500 nodes per XCD partition
constexpr int NCHUNK = 250;             // edge chunks per XCD
constexpr int EPC  = (NE + NCHUNK - 1) / NCHUNK;   // 6400 edges per chunk
constexpr int NB_G = (NN + 63) / 64;    // 1563 gemm/tail tiles
constexpr int KB1  = 24;                // 192/8 k-blocks, W1 MFMA pack
constexpr int KB2  = 16;                // 128/8 k-blocks, W2 MFMA pack

typedef _Float16 f16x8 __attribute__((ext_vector_type(8)));
typedef float    f32x4 __attribute__((ext_vector_type(4)));

__global__ __launch_bounds__(256) void k_zero_cur(int* __restrict__ cur) {
    int i = blockIdx.x * 256 + threadIdx.x;
    if (i < NN) cur[i] = 0;
}

// Weight packs, both MFMA B-layout: Wb[kblk][c] = 8 consecutive-k halves
// of column c. W1: 24 kblks (zero-padded past K=165). W2: 16 kblks exact.
__global__ __launch_bounds__(256) void k_wpack(const float* __restrict__ W1,
                                               const float* __restrict__ W2,
                                               uint4* __restrict__ Wb1,
                                               uint4* __restrict__ Wb2) {
    int idx = blockIdx.x * 256 + threadIdx.x;
    if (idx < KB1 * HID) {
        int kb = idx >> 7, c = idx & 127;
        unsigned u[4];
#pragma unroll
        for (int q = 0; q < 4; ++q) {
            int k0 = kb * 8 + 2 * q;
            float lo = (k0     < FIN) ? W1[(size_t)k0 * HID + c] : 0.0f;
            float hi = (k0 + 1 < FIN) ? W1[(size_t)(k0 + 1) * HID + c] : 0.0f;
            __half2 h = __floats2half2_rn(lo, hi);
            u[q] = __builtin_bit_cast(unsigned, h);
        }
        Wb1[idx] = make_uint4(u[0], u[1], u[2], u[3]);
    } else {
        int j = idx - KB1 * HID;
        if (j >= KB2 * HID) return;
        int kb = j >> 7, c = j & 127;
        unsigned u[4];
#pragma unroll
        for (int q = 0; q < 4; ++q) {
            int k0 = kb * 8 + 2 * q;
            __half2 h = __floats2half2_rn(W2[(size_t)k0 * HID + c],
                                          W2[(size_t)(k0 + 1) * HID + c]);
            u[q] = __builtin_bit_cast(unsigned, h);
        }
        Wb2[j] = make_uint4(u[0], u[1], u[2], u[3]);
    }
}

// XCD-partitioned padded fill: col[d*CAP + slot] = s; cur[d] ends as degree.
__global__ __launch_bounds__(256) void k_fill_pad(const int* __restrict__ src,
                                                  const int* __restrict__ dst,
                                                  int* __restrict__ cur,
                                                  int* __restrict__ col) {
    const int b  = blockIdx.x;
    const int lo = (b & 7) * NPX;
    const int hi = lo + NPX;
    const int q  = b >> 3;
    const int e0 = q * EPC;
    const int e1 = (e0 + EPC < NE) ? e0 + EPC : NE;

    int e = e0 + threadIdx.x;
    for (; e + 3 * 256 < e1; e += 4 * 256) {
        int d0 = __builtin_nontemporal_load(&dst[e]);
        int d1 = __builtin_nontemporal_load(&dst[e + 256]);
        int d2 = __builtin_nontemporal_load(&dst[e + 512]);
        int d3 = __builtin_nontemporal_load(&dst[e + 768]);
        int s0 = __builtin_nontemporal_load(&src[e]);
        int s1 = __builtin_nontemporal_load(&src[e + 256]);
        int s2 = __builtin_nontemporal_load(&src[e + 512]);
        int s3 = __builtin_nontemporal_load(&src[e + 768]);
        if (d0 >= lo && d0 < hi) col[d0 * CAP + atomicAdd(&cur[d0], 1)] = s0;
        if (d1 >= lo && d1 < hi) col[d1 * CAP + atomicAdd(&cur[d1], 1)] = s1;
        if (d2 >= lo && d2 < hi) col[d2 * CAP + atomicAdd(&cur[d2], 1)] = s2;
        if (d3 >= lo && d3 < hi) col[d3 * CAP + atomicAdd(&cur[d3], 1)] = s3;
    }
    for (; e < e1; e += 256) {
        int d = __builtin_nontemporal_load(&dst[e]);
        if (d >= lo && d < hi) {
            int s = __builtin_nontemporal_load(&src[e]);
            col[d * CAP + atomicAdd(&cur[d], 1)] = s;
        }
    }
}

// Layer-1 GEMM via MFMA 16x16x32 f16 (R21-verified mapping).
__global__ __launch_bounds__(256) void k_gemm1m(const float* __restrict__ X,
                                                const uint4* __restrict__ Wb,
                                                const int* __restrict__ cnt,
                                                __half* __restrict__ Yh) {
    constexpr int KPH = 200;               // halves per LDS row (400B)
    __shared__ __half Xs[64 * KPH];        // 25.6 KB
    const int tid = threadIdx.x;
    const long base = (long)blockIdx.x * 64;
    const int rows = (NN - base < 64) ? (int)(NN - base) : 64;

    for (int i = tid; i < rows * FIN; i += 256) {
        int r = i / FIN, c = i % FIN;
        Xs[r * KPH + c] = __float2half(X[base * FIN + i]);
    }
    for (int i = tid; i < 64 * 27; i += 256) {       // zero pad k=165..191
        int r = i / 27, c = FIN + i % 27;
        Xs[r * KPH + c] = __float2half(0.0f);
    }
    if (rows < 64) {
        for (int i = tid; i < (64 - rows) * KPH; i += 256)
            Xs[rows * KPH + i] = __float2half(0.0f);
    }
    __syncthreads();

    const int w   = tid >> 6;              // wave 0..3
    const int l   = tid & 63;
    const int l16 = l & 15;
    const int lq  = l >> 4;

    f32x4 acc[8];
#pragma unroll
    for (int n = 0; n < 8; ++n) acc[n] = (f32x4){0.f, 0.f, 0.f, 0.f};

    const __half* Arow = &Xs[(16 * w + l16) * KPH + lq * 8];
#pragma unroll
    for (int s = 0; s < 6; ++s) {
        f16x8 a = *(const f16x8*)(Arow + s * 32);            // ds_read_b128
        const uint4* bp = &Wb[(4 * s + lq) * HID + l16];
#pragma unroll
        for (int n = 0; n < 8; ++n) {
            f16x8 b = __builtin_bit_cast(f16x8, bp[16 * n]);
            acc[n] = __builtin_amdgcn_mfma_f32_16x16x32_f16(a, b, acc[n], 0, 0, 0);
        }
    }

    long rowR[4];
    float dR[4];
#pragma unroll
    for (int reg = 0; reg < 4; ++reg) {
        rowR[reg] = base + 16 * w + lq * 4 + reg;
        dR[reg] = (rowR[reg] < NN) ? rsqrtf((float)cnt[rowR[reg]] + 1.0f) : 0.f;
    }
#pragma unroll
    for (int n = 0; n < 8; ++n) {
        int colc = 16 * n + l16;
#pragma unroll
        for (int reg = 0; reg < 4; ++reg) {
            if (rowR[reg] < NN)
                Yh[rowR[reg] * HID + colc] = __float2half(acc[n][reg] * dR[reg]);
        }
    }
}

// Gather sum of pre-scaled fp16 rows (incl. self) from padded col rows;
// lane j owns cols 2j,2j+1.
__device__ __forceinline__ void gather_row_h(const __half2* __restrict__ H2,
                                             const int* __restrict__ col,
                                             int i, int cnt, int j,
                                             float& a0, float& a1) {
    const int base = i * CAP;
    float2 self = __half22float2(H2[(size_t)i * 64 + j]);
    a0 = self.x;
    a1 = self.y;
    int k = 0;
    for (; k + 8 <= cnt; k += 8) {
        int s[8];
#pragma unroll
        for (int u = 0; u < 8; ++u)
            s[u] = __builtin_nontemporal_load(&col[base + k + u]);
        __half2 h[8];
#pragma unroll
        for (int u = 0; u < 8; ++u) h[u] = H2[(size_t)s[u] * 64 + j];
#pragma unroll
        for (int u = 0; u < 8; ++u) {
            float2 f = __half22float2(h[u]);
            a0 += f.x;
            a1 += f.y;
        }
    }
    for (; k < cnt; ++k) {
        int cs = __builtin_nontemporal_load(&col[base + k]);
        float2 f = __half22float2(H2[(size_t)cs * 64 + j]);
        a0 += f.x;
        a1 += f.y;
    }
}

// Pure gather, wave per 4 nodes. dinv inline from cnt.
// MODE 0: out = fp16( di * relu(di*a + b1) );  MODE 1: out = fp16( di * a ).
template<int MODE>
__global__ __launch_bounds__(64) void k_aggP(const __half* __restrict__ Hh,
                                             const int* __restrict__ cntA,
                                             const int* __restrict__ col,
                                             const float* __restrict__ bias,
                                             __half* __restrict__ Oh) {
    const int j = threadIdx.x;
    const int base = blockIdx.x * 4;
    const __half2* H2 = (const __half2*)Hh;
    float2 bb = make_float2(0.f, 0.f);
    if (MODE == 0) bb = ((const float2*)bias)[j];

#pragma unroll
    for (int n = 0; n < 4; ++n) {
        const int i = base + n;
        const int cnt = cntA[i];
        const float di = rsqrtf((float)cnt + 1.0f);
        float a0, a1;
        gather_row_h(H2, col, i, cnt, j, a0, a1);
        float r0, r1;
        if (MODE == 0) {
            r0 = di * fmaxf(di * a0 + bb.x, 0.0f);
            r1 = di * fmaxf(di * a1 + bb.y, 0.0f);
        } else {
            r0 = di * a0;
            r1 = di * a1;
        }
        ((__half2*)Oh)[(size_t)i * 64 + j] = __floats2half2_rn(r0, r1);
    }
}

// MFMA tail: q = u @ W2 (16x16x32 f16, 4 K-steps); out = relu(q+b2)@W3+b3.
// Same wave/tile decomposition as k_gemm1m; head via 16-lane shfl reduce.
__global__ __launch_bounds__(256) void k_tailm(const __half* __restrict__ Ug,
                                               const uint4* __restrict__ Wb2,
                                               const float* __restrict__ b2,
                                               const float* __restrict__ W3,
                                               const float* __restrict__ b3,
                                               float* __restrict__ out) {
    constexpr int KPH = 136;               // halves per LDS row (272B)
    __shared__ __half Xs[64 * KPH];        // 17.4 KB
    const int tid = threadIdx.x;
    const long base = (long)blockIdx.x * 64;

    // stage u rows (already fp16): 64 rows x 16 uint4
    for (int li = tid; li < 64 * 16; li += 256) {
        int row = li >> 4, q4 = li & 15;
        uint4 v = make_uint4(0, 0, 0, 0);
        if (base + row < NN)
            v = *(const uint4*)&Ug[(base + row) * HID + q4 * 8];
        *(uint4*)&Xs[row * KPH + q4 * 8] = v;
    }
    __syncthreads();

    const int w   = tid >> 6;
    const int l   = tid & 63;
    const int l16 = l & 15;
    const int lq  = l >> 4;

    f32x4 acc[8];
#pragma unroll
    for (int n = 0; n < 8; ++n) acc[n] = (f32x4){0.f, 0.f, 0.f, 0.f};

    const __half* Arow = &Xs[(16 * w + l16) * KPH + lq * 8];
#pragma unroll
    for (int s = 0; s < 4; ++s) {
        f16x8 a = *(const f16x8*)(Arow + s * 32);
        const uint4* bp = &Wb2[(4 * s + lq) * HID + l16];
#pragma unroll
        for (int n = 0; n < 8; ++n) {
            f16x8 b = __builtin_bit_cast(f16x8, bp[16 * n]);
            acc[n] = __builtin_amdgcn_mfma_f32_16x16x32_f16(a, b, acc[n], 0, 0, 0);
        }
    }

    // head: per lane, cols c = 16n + l16; rows = base + 16w + lq*4 + reg
    float w30[8], w31[8], bbv[8];
#pragma unroll
    for (int n = 0; n < 8; ++n) {
        int c = 16 * n + l16;
        float2 w3v = *(const float2*)&W3[c * 2];
        w30[n] = w3v.x;
        w31[n] = w3v.y;
        bbv[n] = b2[c];
    }
    const float b30 = b3[0], b31 = b3[1];

#pragma unroll
    for (int reg = 0; reg < 4; ++reg) {
        long row = base + 16 * w + lq * 4 + reg;
        float p0 = 0.f, p1 = 0.f;
#pragma unroll
        for (int n = 0; n < 8; ++n) {
            float h = fmaxf(acc[n][reg] + bbv[n], 0.0f);
            p0 += h * w30[n];
            p1 += h * w31[n];
        }
#pragma unroll
        for (int m = 1; m < 16; m <<= 1) {
            p0 += __shfl_xor(p0, m);
            p1 += __shfl_xor(p1, m);
        }
        if (l16 == 0 && row < NN)
            ((float2*)out)[row] = make_float2(p0 + b30, p1 + b31);
    }
}

extern "C" void kernel_launch(void* const* d_in, const int* in_sizes, int n_in,
                              void* d_out, int out_size, void* d_ws, size_t ws_size,
                              hipStream_t stream) {
    const float* x   = (const float*)d_in[0];
    const int*   ei  = (const int*)d_in[1];
    const float* W1  = (const float*)d_in[2];
    const float* b1  = (const float*)d_in[3];
    const float* W2  = (const float*)d_in[4];
    const float* b2  = (const float*)d_in[5];
    const float* W3  = (const float*)d_in[6];
    const float* b3  = (const float*)d_in[7];
    float* out = (float*)d_out;

    const int* srcA = ei;
    const int* dstA = ei + NE;

    char* p = (char*)d_ws;
    auto alloc = [&](size_t bytes) {
        char* r = p;
        p += (bytes + 255) & ~(size_t)255;
        return r;
    };
    int*      cur    = (int*)  alloc(NN * 4);        // cursor == degree
    int*      col    = (int*)  alloc((size_t)NN * CAP * 4);   // padded 25.6MB
    uint4*    wb1    = (uint4*)alloc((size_t)KB1 * HID * 16); // 49KB
    uint4*    wb2    = (uint4*)alloc((size_t)KB2 * HID * 16); // 32KB
    __half*   hhat   = (__half*)alloc((size_t)NN * HID * 2);  // dinv*h1
    __half*   h2hat  = (__half*)alloc((size_t)NN * HID * 2);  // dinv*h2
    __half*   ubuf   = (__half*)alloc((size_t)NN * HID * 2);  // A-hat h2

    const int nb_n  = (NN + 255) / 256;
    const int nb_wp = ((KB1 + KB2) * HID + 255) / 256;

    // ---- padded CSR fill (cursor == histogram) + weight packs ----
    k_zero_cur<<<nb_n, 256, 0, stream>>>(cur);
    k_wpack<<<nb_wp, 256, 0, stream>>>(W1, W2, wb1, wb2);
    k_fill_pad<<<8 * NCHUNK, 256, 0, stream>>>(srcA, dstA, cur, col);

    // ---- layer 1 GEMM (MFMA) -> hhat ----
    k_gemm1m<<<NB_G, 256, 0, stream>>>(x, wb1, cur, hhat);

    // ---- agg1 (pure) -> h2hat ----
    k_aggP<0><<<NN / 4, 64, 0, stream>>>(hhat, cur, col, b1, h2hat);

    // ---- agg2 (pure) -> u ----
    k_aggP<1><<<NN / 4, 64, 0, stream>>>(h2hat, cur, col, nullptr, ubuf);

    // ---- MFMA tail: relu(u@W2+b2)@W3+b3 ----
    k_tailm<<<NB_G, 256, 0, stream>>>(ubuf, wb2, b2, W3, b3, out);
}